// Round 11
// baseline (576.463 us; speedup 1.0000x reference)
//
#include <hip/hip_runtime.h>
#include <cstdint>

// Problem constants (static per reference)
#define T_TOK 16384     // B*S
#define HD    1024      // H
#define NE    8         // experts
#define CAP   2560      // ceil(1.25*T/E)
#define NCHUNK (T_TOK / 64)   // 256

typedef __attribute__((ext_vector_type(4))) float f32x4;
typedef __attribute__((ext_vector_type(8))) short bf16x8;   // 8 bf16 = 4 VGPRs

__device__ __forceinline__ unsigned short f2bf(float f) {
    union { float f; unsigned u; } x{f};
    unsigned r = x.u + 0x7FFF + ((x.u >> 16) & 1);   // RNE
    return (unsigned short)(r >> 16);
}

__device__ __forceinline__ void gload_lds16(const unsigned short* g, unsigned short* l) {
    __builtin_amdgcn_global_load_lds(
        (const __attribute__((address_space(1))) void*)g,
        (__attribute__((address_space(3))) void*)l, 16, 0, 0);
}

// One phase: ds-read the kk fragments, barrier (lockstep), prio-boosted
// 16-MFMA cluster. Stages are issued by the CALLER before this (in-flight
// across the barrier). Post-MFMA barrier/vmcnt also in the caller.
__device__ __forceinline__ void phase_mfma(
    const unsigned short (&A)[256][64], const unsigned short (&B)[128][64],
    f32x4 (&acc)[4][4], int wm, int wn, int fr, int kg, int kk)
{
    bf16x8 af[4], bfr[4];
    #pragma unroll
    for (int i2 = 0; i2 < 4; ++i2) {
        int R = wm * 64 + i2 * 16 + fr;
        af[i2] = *(const bf16x8*)&A[R][((kk * 4 + kg) ^ (R & 7)) * 8];
    }
    #pragma unroll
    for (int j2 = 0; j2 < 4; ++j2) {
        int R = wn * 64 + j2 * 16 + fr;
        bfr[j2] = *(const bf16x8*)&B[R][((kk * 4 + kg) ^ (R & 7)) * 8];
    }
    __builtin_amdgcn_s_barrier();          // all waves staged+read-issued
    __builtin_amdgcn_s_setprio(1);
    #pragma unroll
    for (int i2 = 0; i2 < 4; ++i2)
        #pragma unroll
        for (int j2 = 0; j2 < 4; ++j2)
            acc[i2][j2] = __builtin_amdgcn_mfma_f32_16x16x32_bf16(
                af[i2], bfr[j2], acc[i2][j2], 0, 0, 0);
    __builtin_amdgcn_s_setprio(0);
}

// ---------------------------------------------------------------------------
// bf16 MFMA GEMM: C[M,N] = op(A[M,K] @ Bt[N,K]^T + bias[N])
// R11: 256x128 tile, BK=64, 8 waves (4m x 2n), TRIPLE-buffered LDS with
// distance-2 prefetch + counted vmcnt (never 0 in main loop) + 2 phases/step
// of {stage||ds_read -> barrier -> setprio(1) 16xMFMA setprio(0)}.
//   liveness: buf[b] holds tile t==b(mod3); staged at t-2, read at t,
//   prior occupant's reads ended at t-3 (step-end barrier) -> no overlap.
//   wait: end-of-step-t vmcnt(6) waits only tile (t+1)'s 6 loads (2 steps
//   old); tile (t+2)'s 6 stay in flight. Peeled final step uses vmcnt(0).
// - XCD-aware bijective block swizzle; XOR chunk-swizzle (0 conflicts, R6).
// - Expert tiles: empty-suffix early-exit (idxTab[m0]<0 => whole tile empty;
//   FC1's h rows for those slots are never read by FC2's matching tile).
// ---------------------------------------------------------------------------
template<bool GATHER, bool RELU, bool ROWSCALE, bool SCATTER, bool OUTBF16>
__global__ __launch_bounds__(512)
void gemm_bf16_k(const unsigned short* __restrict__ A,
                 const unsigned short* __restrict__ Bt,
                 const float* __restrict__ bias,
                 void* __restrict__ Cv,
                 int M, int N, int K,
                 const int* __restrict__ idxTab,
                 const float* __restrict__ rs,
                 const float* __restrict__ addsrc,
                 long aB, long bB, long biasB, long tabB, long cB)
{
    // ---- XCD-aware remap: XCD c gets contiguous logical chunk ----
    const int nx = gridDim.x, ny = gridDim.y;
    long nwg = (long)nx * ny * gridDim.z;
    long flat = blockIdx.x + (long)nx * (blockIdx.y + (long)ny * blockIdx.z);
    long cpx = nwg >> 3;                       // nwg % 8 == 0 by construction
    long swz = (flat & 7) * cpx + (flat >> 3);
    const int bx = (int)(swz % nx);
    const int by = (int)((swz / nx) % ny);
    const int bz = (int)(swz / ((long)nx * ny));

    A  += (long)bz * aB;
    Bt += (long)bz * bB;
    const float* bptr = bias + (long)bz * biasB;
    const int* tab = idxTab ? idxTab + (long)bz * tabB : nullptr;
    float*          Cf = (float*)Cv + (long)bz * cB;
    unsigned short* Cb = (unsigned short*)Cv + (long)bz * cB;

    const int m0 = by * 256, n0 = bx * 128;

    // empty-suffix early-exit (before any barrier; uniform across block)
    if ((GATHER || SCATTER) && tab[m0] < 0) return;

    __shared__ unsigned short As[3][256][64];   // 96 KB
    __shared__ unsigned short Bs[3][128][64];   // 48 KB (144 KB total)

    const int tid  = threadIdx.x;
    const int wv   = tid >> 6;               // 0..7
    const int lane = tid & 63;

    // staging: issue = 8 rows x 128 B = 1024 B = 64 lanes x 16 B.
    const int srow = lane >> 3;
    const int schk = lane & 7;

    const unsigned short* aSrc[4];           // wave stages A rows wv*32..+31
    const unsigned short* bSrc[2];           // wave stages B rows wv*16..+15
    int aRow[4], bRow[2];
    #pragma unroll
    for (int i = 0; i < 4; ++i) {
        int lrow = wv * 32 + i * 8 + srow;          // 0..255
        int scol = ((schk ^ (lrow & 7)) * 8);       // swizzled col (elems)
        long sr;
        if (GATHER) { int tr = tab[m0 + lrow]; sr = tr < 0 ? 0 : tr; }
        else        sr = m0 + lrow;
        aSrc[i] = A + sr * (long)K + scol;
        aRow[i] = wv * 32 + i * 8;
    }
    #pragma unroll
    for (int i = 0; i < 2; ++i) {
        int lrow = wv * 16 + i * 8 + srow;          // 0..127
        int scol = ((schk ^ (lrow & 7)) * 8);
        bSrc[i] = Bt + (long)(n0 + lrow) * K + scol;
        bRow[i] = wv * 16 + i * 8;
    }

    f32x4 acc[4][4] = {};
    const int wm = wv >> 1, wn = wv & 1;     // 4 x 2 wave grid
    const int fr = lane & 15, kg = lane >> 4;
    const int NT = K >> 6;                   // 16 for K=1024

    // prologue: stage steps 0 (buf0) and 1 (buf1); wait step-0 only
    #pragma unroll
    for (int i = 0; i < 4; ++i) gload_lds16(aSrc[i],      &As[0][aRow[i]][0]);
    #pragma unroll
    for (int i = 0; i < 2; ++i) gload_lds16(bSrc[i],      &Bs[0][bRow[i]][0]);
    #pragma unroll
    for (int i = 0; i < 4; ++i) gload_lds16(aSrc[i] + 64, &As[1][aRow[i]][0]);
    #pragma unroll
    for (int i = 0; i < 2; ++i) gload_lds16(bSrc[i] + 64, &Bs[1][bRow[i]][0]);
    asm volatile("s_waitcnt vmcnt(6)" ::: "memory");   // step 0 landed
    __builtin_amdgcn_s_barrier();

    for (int t = 0; t < NT - 1; ++t) {
        const int rb = t % 3;
        const int sb = (t + 2) % 3;
        const bool doStage = (t + 2) < NT;
        const int k0s = (t + 2) << 6;

        // phase kk=0: stage first half of t+2, compute kk0
        if (doStage) {
            gload_lds16(aSrc[0] + k0s, &As[sb][aRow[0]][0]);
            gload_lds16(aSrc[1] + k0s, &As[sb][aRow[1]][0]);
            gload_lds16(bSrc[0] + k0s, &Bs[sb][bRow[0]][0]);
        }
        phase_mfma(As[rb], Bs[rb], acc, wm, wn, fr, kg, 0);
        __builtin_amdgcn_s_barrier();

        // phase kk=1: stage second half of t+2, compute kk1
        if (doStage) {
            gload_lds16(aSrc[2] + k0s, &As[sb][aRow[2]][0]);
            gload_lds16(aSrc[3] + k0s, &As[sb][aRow[3]][0]);
            gload_lds16(bSrc[1] + k0s, &Bs[sb][bRow[1]][0]);
        }
        phase_mfma(As[rb], Bs[rb], acc, wm, wn, fr, kg, 1);
        // end-of-step wait: tile t+1's 6 loads (issued at t-1) must land;
        // tile t+2's 6 (just issued) stay in flight. Last prefetched step
        // has nothing younger -> full drain.
        if (t == NT - 2) asm volatile("s_waitcnt vmcnt(0)" ::: "memory");
        else             asm volatile("s_waitcnt vmcnt(6)" ::: "memory");
        __builtin_amdgcn_s_barrier();
    }
    // peeled final step (no stages, no trailing wait)
    {
        const int rb = (NT - 1) % 3;
        phase_mfma(As[rb], Bs[rb], acc, wm, wn, fr, kg, 0);
        __builtin_amdgcn_s_barrier();
        phase_mfma(As[rb], Bs[rb], acc, wm, wn, fr, kg, 1);
    }

    // epilogue: C/D layout col = lane&15, row = (lane>>4)*4 + r
    const int colL = lane & 15, rgrp = (lane >> 4) * 4;
    #pragma unroll
    for (int i2 = 0; i2 < 4; ++i2) {
        #pragma unroll
        for (int r = 0; r < 4; ++r) {
            int gm = m0 + wm * 64 + i2 * 16 + rgrp + r;
            int token = gm; float sc = 1.0f;
            if (SCATTER) {
                token = tab[gm];
                if (token < 0) continue;
                sc = rs[token];
            } else if (ROWSCALE) {
                sc = rs[gm];
            }
            #pragma unroll
            for (int j2 = 0; j2 < 4; ++j2) {
                int gn = n0 + wn * 64 + j2 * 16 + colL;
                float v = acc[i2][j2][r] + bptr[gn];
                if (RELU) v = fmaxf(v, 0.0f);
                if (SCATTER) {
                    long idx = (long)token * N + gn;
                    if (OUTBF16) Cb[idx] = f2bf(addsrc[idx] + v * sc);  // fused cast
                    else         Cf[idx] += v * sc;                     // f32 RMW
                } else {
                    if (ROWSCALE) v *= sc;
                    if (OUTBF16) Cb[(long)gm * N + gn] = f2bf(v);
                    else         Cf[(long)gm * N + gn] = v;
                }
            }
        }
    }
}

// ---------------------------------------------------------------------------
// Dropped-token rows: mixb[row] = bf16(mix[row]) for rows never touched by
// the scatter GEMM.
// ---------------------------------------------------------------------------
__global__ __launch_bounds__(256)
void drop_cast_k(const float* __restrict__ mix, unsigned short* __restrict__ mixb,
                 const int* __restrict__ droplist, const int* __restrict__ dropcnt)
{
    const int cnt = *dropcnt;
    for (int i = blockIdx.x; i < cnt; i += gridDim.x) {
        const int tok = droplist[i];
        const float4* src = (const float4*)(mix + (long)tok * HD);
        ushort4* dst = (ushort4*)(mixb + (long)tok * HD);
        const int j = threadIdx.x;          // 256 threads x 4 elems = 1024
        float4 v = src[j];
        ushort4 o;
        o.x = f2bf(v.x); o.y = f2bf(v.y); o.z = f2bf(v.z); o.w = f2bf(v.w);
        dst[j] = o;
    }
}

// ---------------------------------------------------------------------------
// Transpose + cast: W[K][N] f32 -> Wt[N][K] bf16, 64x64 LDS tiles. z batched.
// ---------------------------------------------------------------------------
__global__ __launch_bounds__(256)
void transpose_cast_k(const float* __restrict__ W, unsigned short* __restrict__ Wt,
                      int K, int N, long wB, long wtB)
{
    const int z = blockIdx.z;
    W  += (long)z * wB;
    Wt += (long)z * wtB;
    __shared__ float tile[64][65];
    const int k0 = blockIdx.x * 64, n0 = blockIdx.y * 64;
    const int c = threadIdx.x & 63, r4 = threadIdx.x >> 6;
    #pragma unroll 4
    for (int it = 0; it < 16; ++it) {
        int row = it * 4 + r4;
        tile[row][c] = W[(long)(k0 + row) * N + n0 + c];
    }
    __syncthreads();
    #pragma unroll 4
    for (int it = 0; it < 16; ++it) {
        int nrow = it * 4 + r4;
        Wt[(long)(n0 + nrow) * K + k0 + c] = f2bf(tile[c][nrow]);
    }
}

// ---------------------------------------------------------------------------
// Wsmall: Wg'[H][8] = W_in @ W_gate, Wc'[H][2] = W_in @ W_coef  (f32)
// ---------------------------------------------------------------------------
__global__ __launch_bounds__(256)
void wsmall_k(const float* __restrict__ W_in, const float* __restrict__ W_gate,
              const float* __restrict__ W_coef,
              float* __restrict__ wgp, float* __restrict__ wcp)
{
    const int r = blockIdx.x * 4 + (threadIdx.x >> 6);
    const int lane = threadIdx.x & 63;
    float s[10] = {};
    for (int k = lane; k < HD; k += 64) {
        float a = W_in[(long)r * HD + k];
        const float4* g = (const float4*)(W_gate + (long)k * 8);
        float4 g0 = g[0], g1 = g[1];
        s[0] += a * g0.x; s[1] += a * g0.y; s[2] += a * g0.z; s[3] += a * g0.w;
        s[4] += a * g1.x; s[5] += a * g1.y; s[6] += a * g1.z; s[7] += a * g1.w;
        float2 cv = *(const float2*)(W_coef + (long)k * 2);
        s[8] += a * cv.x; s[9] += a * cv.y;
    }
    #pragma unroll
    for (int off = 32; off > 0; off >>= 1)
        #pragma unroll
        for (int e = 0; e < 10; ++e) s[e] += __shfl_xor(s[e], off);
    if (lane == 0) {
        #pragma unroll
        for (int e = 0; e < 8; ++e) wgp[(long)r * 8 + e] = s[e];
        wcp[(long)r * 2 + 0] = s[8];
        wcp[(long)r * 2 + 1] = s[9];
    }
}

// bg[8] = b_in @ W_gate ; bc[2] = b_in @ W_coef + b_coef
__global__ void gbias_k(const float* __restrict__ b_in, const float* __restrict__ W_gate,
                        const float* __restrict__ W_coef, const float* __restrict__ b_coef,
                        float* __restrict__ bg, float* __restrict__ bc)
{
    const int lane = threadIdx.x;  // 64
    float s[10] = {};
    for (int k = lane; k < HD; k += 64) {
        float a = b_in[k];
        const float4* g = (const float4*)(W_gate + (long)k * 8);
        float4 g0 = g[0], g1 = g[1];
        s[0] += a * g0.x; s[1] += a * g0.y; s[2] += a * g0.z; s[3] += a * g0.w;
        s[4] += a * g1.x; s[5] += a * g1.y; s[6] += a * g1.z; s[7] += a * g1.w;
        float2 cv = *(const float2*)(W_coef + (long)k * 2);
        s[8] += a * cv.x; s[9] += a * cv.y;
    }
    #pragma unroll
    for (int off = 32; off > 0; off >>= 1)
        #pragma unroll
        for (int e = 0; e < 10; ++e) s[e] += __shfl_xor(s[e], off);
    if (lane == 0) {
        #pragma unroll
        for (int e = 0; e < 8; ++e) bg[e] = s[e];
        bc[0] = s[8] + b_coef[0];
        bc[1] = s[9] + b_coef[1];
    }
}

// ---------------------------------------------------------------------------
// Gating from x with fused weights (one wave per token) + fused x->bf16 cast.
// ---------------------------------------------------------------------------
__global__ __launch_bounds__(256)
void gating_k(const float* __restrict__ x,
              const float* __restrict__ Wg,   // [H,8] fused
              const float* __restrict__ Wc,   // [H,2] fused
              const float* __restrict__ bg,   // [8]
              const float* __restrict__ bc,   // [2]
              unsigned short* __restrict__ xb,
              int* __restrict__ eidx,
              float* __restrict__ gval,
              float* __restrict__ coef0,
              float* __restrict__ coef1)
{
    const int tok = (blockIdx.x * 256 + threadIdx.x) >> 6;
    const int lane = threadIdx.x & 63;
    const float* row = x + (long)tok * HD;
    unsigned short* orow = xb + (long)tok * HD;

    float acc[8] = {};
    float c0 = 0.f, c1 = 0.f;
    for (int i = 0; i < HD / 64; ++i) {
        int k = i * 64 + lane;
        float tv = row[k];
        orow[k] = f2bf(tv);                      // fused x -> bf16 (coalesced)
        const float4* wg = (const float4*)(Wg + (long)k * 8);
        float4 w0 = wg[0], w1 = wg[1];
        acc[0] = fmaf(tv, w0.x, acc[0]); acc[1] = fmaf(tv, w0.y, acc[1]);
        acc[2] = fmaf(tv, w0.z, acc[2]); acc[3] = fmaf(tv, w0.w, acc[3]);
        acc[4] = fmaf(tv, w1.x, acc[4]); acc[5] = fmaf(tv, w1.y, acc[5]);
        acc[6] = fmaf(tv, w1.z, acc[6]); acc[7] = fmaf(tv, w1.w, acc[7]);
        float2 wcv = *(const float2*)(Wc + (long)k * 2);
        c0 = fmaf(tv, wcv.x, c0);
        c1 = fmaf(tv, wcv.y, c1);
    }
    #pragma unroll
    for (int off = 32; off > 0; off >>= 1) {
        #pragma unroll
        for (int e = 0; e < 8; ++e) acc[e] += __shfl_xor(acc[e], off);
        c0 += __shfl_xor(c0, off);
        c1 += __shfl_xor(c1, off);
    }
    if (lane == 0) {
        #pragma unroll
        for (int e = 0; e < 8; ++e) acc[e] += bg[e];
        float m = acc[0]; int best = 0;
        #pragma unroll
        for (int e = 1; e < 8; ++e) if (acc[e] > m) { m = acc[e]; best = e; }
        float s = 0.f;
        #pragma unroll
        for (int e = 0; e < 8; ++e) s += expf(acc[e] - m);
        eidx[tok] = best;
        gval[tok] = 1.0f / s;
        float l0 = c0 + bc[0], l1 = c1 + bc[1];
        float mm = fmaxf(l0, l1);
        float e0 = expf(l0 - mm), e1 = expf(l1 - mm);
        float inv = 1.0f / (e0 + e1);
        coef0[tok] = e0 * inv;
        coef1[tok] = e1 * inv;
    }
}

// ---------------------------------------------------------------------------
// Parallel capacity scan, 3 phases (integer-exact, verified round 5).
// ---------------------------------------------------------------------------
__global__ void scan_hist_k(const int* __restrict__ eidx,
                            int* __restrict__ counts,
                            int* __restrict__ idxTab)
{
    const int b = blockIdx.x;          // chunk id, 0..255
    const int lane = threadIdx.x;      // 64
    for (int j = b * 64 + lane; j < NE * CAP; j += NCHUNK * 64)
        idxTab[j] = -1;
    int e = eidx[b * 64 + lane];
    #pragma unroll
    for (int ex = 0; ex < NE; ++ex) {
        unsigned long long msk = __ballot(e == ex);
        if (lane == ex) counts[b * NE + ex] = (int)__popcll(msk);
    }
}

__global__ void scan_offsets_k(const int* __restrict__ counts,
                               int* __restrict__ offsets,
                               int* __restrict__ dropcnt)
{
    const int e = threadIdx.x;         // 64 threads, 8 active
    if (e == 63) *dropcnt = 0;         // runs before scan_fill_k
    if (e < NE) {
        int run = 0;
        for (int b = 0; b < NCHUNK; ++b) {
            offsets[b * NE + e] = run;
            run += counts[b * NE + e];
        }
    }
}

__global__ void scan_fill_k(const int* __restrict__ eidx,
                            const float* __restrict__ gval,
                            const float* __restrict__ coef0,
                            const int* __restrict__ offsets,
                            int* __restrict__ idxTab,
                            float* __restrict__ smoe,
                            int* __restrict__ droplist,
                            int* __restrict__ dropcnt)
{
    const int b = blockIdx.x;
    const int lane = threadIdx.x;
    const int tok = b * 64 + lane;
    int e = eidx[tok];
    unsigned long long below = (lane == 0) ? 0ull : ((~0ull) >> (64 - lane));
    int myrank = 0;
    #pragma unroll
    for (int ex = 0; ex < NE; ++ex) {
        unsigned long long msk = __ballot(e == ex);
        if (e == ex) myrank = (int)__popcll(msk & below) + offsets[b * NE + ex];
    }
    if (myrank < CAP) {
        idxTab[e * CAP + myrank] = tok;
        smoe[tok] = gval[tok] * coef0[tok];
    } else {
        smoe[tok] = 0.0f;
        int di = atomicAdd(dropcnt, 1);    // order varies; content is a set
        droplist[di] = tok;
    }
}

// ---------------------------------------------------------------------------
// Workspace plan (lifetime-aliased; ~135 MB):
//   slotA [0,32Mi):   W1T then res1 then mixb
//   h     [32,72Mi);  t_b [72,104Mi); W2T [104,120Mi);
//   WinT/Wr1T/Wr2T/WoutT [120..128Mi); small [128Mi..)
//   xb: d_out[0,32Mi);  mix: d_out f32 (read-only after j);  out: d_out
// ---------------------------------------------------------------------------
extern "C" void kernel_launch(void* const* d_in, const int* in_sizes, int n_in,
                              void* d_out, int out_size, void* d_ws, size_t ws_size,
                              hipStream_t stream)
{
    const float* x      = (const float*)d_in[0];
    const float* W_in   = (const float*)d_in[1];
    const float* b_in   = (const float*)d_in[2];
    const float* W_gate = (const float*)d_in[3];
    const float* W1     = (const float*)d_in[4];
    const float* b1     = (const float*)d_in[5];
    const float* W2     = (const float*)d_in[6];
    const float* b2     = (const float*)d_in[7];
    const float* Wr1    = (const float*)d_in[8];
    const float* br1    = (const float*)d_in[9];
    const float* Wr2    = (const float*)d_in[10];
    const float* br2    = (const float*)d_in[11];
    const float* W_coef = (const float*)d_in[12];
    const float* b_coef = (const float*)d_in[13];
    const float* W_out  = (const float*)d_in[14];
    const float* b_out  = (const float*)d_in[15];
    float* out = (float*)d_out;

    const size_t MiB = 1024 * 1024;
    char* ws = (char*)d_ws;
    unsigned short* W1T  = (unsigned short*)(ws + 0);          // 16 MiB
    unsigned short* res1 = (unsigned short*)(ws + 0);          // 32 MiB (after FC1)
    unsigned short* mixb = (unsigned short*)(ws + 0);          // 32 MiB (after res-mix)
    unsigned short* h    = (unsigned short*)(ws + 32 * MiB);   // 40 MiB
    unsigned short* t_b  = (unsigned short*)(ws + 72 * MiB);   // 32 MiB
    unsigned short* W2T  = (unsigned short*)(ws + 104 * MiB);  // 16 MiB
    unsigned short* WinT = (unsigned short*)(ws + 120 * MiB);  // 2 MiB
    unsigned short* Wr1T = (unsigned short*)(ws + 122 * MiB);  // 2 MiB
    unsigned short* Wr2T = (unsigned short*)(ws + 124 * MiB);  // 2 MiB
    unsigned short* WoutT= (unsigned short*)(ws + 126 * MiB);  // 2 MiB
    char* sm = ws + 128 * MiB;
    float* wgp  = (float*)(sm);            sm += HD * 8 * 4;
    float* wcp  = (float*)(sm);            sm += HD * 2 * 4;
    float* bg   = (float*)(sm);            sm += 64;
    float* bc   = (float*)(sm);            sm += 64;
    int*   eidx = (int*)(sm);              sm += T_TOK * 4;
    float* gval = (float*)(sm);            sm += T_TOK * 4;
    float* cf0  = (float*)(sm);            sm += T_TOK * 4;
    float* cf1  = (float*)(sm);            sm += T_TOK * 4;
    float* smoe = (float*)(sm);            sm += T_TOK * 4;
    int* idxTab = (int*)(sm);              sm += NE * CAP * 4;
    int* counts = (int*)(sm);              sm += NCHUNK * NE * 4;
    int* offs   = (int*)(sm);              sm += NCHUNK * NE * 4;
    int* droplist = (int*)(sm);            sm += T_TOK * 4;
    int* dropcnt  = (int*)(sm);            sm += 64;
    unsigned short* xb = (unsigned short*)d_out;   // 32 MiB, dies after f
    float* mix = out;                               // f32, written j, read k/m
    (void)ws_size; (void)in_sizes; (void)n_in; (void)out_size;

    dim3 blk(256);
    dim3 blkG(512);
    dim3 gT(16, 16, 1);
    dim3 gT8(16, 16, 8);
    dim3 gBig(HD / 128, T_TOK / 256, 1);   // 8 x 64 = 512 blocks (%8==0)
    dim3 gExp(HD / 128, CAP / 256, NE);    // 8 x 10 x 8 = 640 blocks (%8==0)

    // b. weight transposes (bf16 [N][K])
    transpose_cast_k<<<gT,  blk, 0, stream>>>(W_in,  WinT,  HD, HD, 0, 0);
    transpose_cast_k<<<gT,  blk, 0, stream>>>(Wr1,   Wr1T,  HD, HD, 0, 0);
    transpose_cast_k<<<gT,  blk, 0, stream>>>(Wr2,   Wr2T,  HD, HD, 0, 0);
    transpose_cast_k<<<gT,  blk, 0, stream>>>(W_out, WoutT, HD, HD, 0, 0);
    transpose_cast_k<<<gT8, blk, 0, stream>>>(W1, W1T, HD, HD, (long)HD * HD, (long)HD * HD);
    transpose_cast_k<<<gT8, blk, 0, stream>>>(W2, W2T, HD, HD, (long)HD * HD, (long)HD * HD);
    // c. fused gating weights (f32)
    wsmall_k<<<HD / 4, blk, 0, stream>>>(W_in, W_gate, W_coef, wgp, wcp);
    gbias_k<<<1, 64, 0, stream>>>(b_in, W_gate, W_coef, b_coef, bg, bc);
    // d. gating from x (f32 routing path) + fused x->bf16 cast
    gating_k<<<T_TOK / 4, blk, 0, stream>>>(x, wgp, wcp, bg, bc, xb,
                                            eidx, gval, cf0, cf1);
    // e. parallel capacity scan (+ dropped-token list)
    scan_hist_k<<<NCHUNK, 64, 0, stream>>>(eidx, counts, idxTab);
    scan_offsets_k<<<1, 64, 0, stream>>>(counts, offs, dropcnt);
    scan_fill_k<<<NCHUNK, 64, 0, stream>>>(eidx, gval, cf0, offs, idxTab, smoe,
                                           droplist, dropcnt);
    // f. t_b = bf16(xb @ W_in + b_in)
    gemm_bf16_k<false, false, false, false, true><<<gBig, blkG, 0, stream>>>(
        xb, WinT, b_in, t_b, T_TOK, HD, HD, nullptr, nullptr, nullptr,
        0, 0, 0, 0, 0);
    // h. h[e] = relu(gather(t_b) @ W1[e] + b1[e])   bf16 out, empty-tile exit
    gemm_bf16_k<true, true, false, false, true><<<gExp, blkG, 0, stream>>>(
        t_b, W1T, b1, h, CAP, HD, HD, idxTab, nullptr, nullptr,
        0, (long)HD * HD, HD, CAP, (long)CAP * HD);
    // i. res1 = relu(t_b @ Wr1 + br1)   bf16 out (overlays W1T slot)
    gemm_bf16_k<false, true, false, false, true><<<gBig, blkG, 0, stream>>>(
        t_b, Wr1T, br1, res1, T_TOK, HD, HD, nullptr, nullptr, nullptr,
        0, 0, 0, 0, 0);
    // j. mix = (res1 @ Wr2 + br2) * cf1[row]   f32 -> d_out
    gemm_bf16_k<false, false, true, false, false><<<gBig, blkG, 0, stream>>>(
        res1, Wr2T, br2, mix, T_TOK, HD, HD, nullptr, cf1, nullptr,
        0, 0, 0, 0, 0);
    // k. mixb[tok] = bf16(mix[tok] + (h[e]@W2[e]+b2[e])*smoe[tok])  fused cast
    gemm_bf16_k<false, false, false, true, true><<<gExp, blkG, 0, stream>>>(
        h, W2T, b2, mixb, CAP, HD, HD, idxTab, smoe, mix,
        (long)CAP * HD, (long)HD * HD, HD, CAP, 0);
    // k2. dropped-token rows: mixb = bf16(mix)
    drop_cast_k<<<256, blk, 0, stream>>>(mix, mixb, droplist, dropcnt);
    // m. out = mixb @ W_out + b_out   f32 -> d_out
    gemm_bf16_k<false, false, false, false, false><<<gBig, blkG, 0, stream>>>(
        mixb, WoutT, b_out, out, T_TOK, HD, HD, nullptr, nullptr, nullptr,
        0, 0, 0, 0, 0);
}

// Round 12
// 404.620 us; speedup vs baseline: 1.4247x; 1.4247x over previous
//
#include <hip/hip_runtime.h>
#include <cstdint>

// Problem constants (static per reference)
#define T_TOK 16384     // B*S
#define HD    1024      // H
#define NE    8         // experts
#define CAP   2560      // ceil(1.25*T/E)
#define NCHUNK (T_TOK / 64)   // 256

typedef __attribute__((ext_vector_type(4))) float f32x4;
typedef __attribute__((ext_vector_type(8))) short bf16x8;   // 8 bf16 = 4 VGPRs

__device__ __forceinline__ unsigned short f2bf(float f) {
    union { float f; unsigned u; } x{f};
    unsigned r = x.u + 0x7FFF + ((x.u >> 16) & 1);   // RNE
    return (unsigned short)(r >> 16);
}

__device__ __forceinline__ void gload_lds16(const unsigned short* g, unsigned short* l) {
    __builtin_amdgcn_global_load_lds(
        (const __attribute__((address_space(1))) void*)g,
        (__attribute__((address_space(3))) void*)l, 16, 0, 0);
}

// ---------------------------------------------------------------------------
// bf16 MFMA GEMM: C[M,N] = op(A[M,K] @ Bt[N,K]^T + bias[N])
// R12 = R10 structure exactly (best measured: 405us total, ~80us/GEMM):
// 256x128 tile, BK=64, 8 waves (4m x 2n), SINGLE-buffer 2-barrier loop.
// R7/R8/R11 pipelining variants all regressed (occupancy loss / lockstep
// stalls); this plain loop is the measured local optimum for these shapes.
// - XCD-aware bijective block swizzle (FETCH 206->70MB, R6).
// - 128B LDS rows + 16B-chunk XOR swizzle, pre-swizzled global source +
//   swizzled ds_read, linear gload_lds dest (0 bank conflicts, R6).
// - R12 new: empty-tile early-exit for expert GEMMs. Slots fill contiguously
//   so idxTab[e][m0]<0 => whole 256-row tile empty. FC1 skips writing exactly
//   the h rows FC2 skips reading (same tab criterion); kept tokens always
//   live in tiles with tab[m0]>=0; dropped tokens handled by drop_cast_k.
// - SCATTER+OUTBF16: fused bf16 C = f2bf(addsrc + v*sc) (R10).
// ---------------------------------------------------------------------------
template<bool GATHER, bool RELU, bool ROWSCALE, bool SCATTER, bool OUTBF16>
__global__ __launch_bounds__(512)
void gemm_bf16_k(const unsigned short* __restrict__ A,
                 const unsigned short* __restrict__ Bt,
                 const float* __restrict__ bias,
                 void* __restrict__ Cv,
                 int M, int N, int K,
                 const int* __restrict__ idxTab,
                 const float* __restrict__ rs,
                 const float* __restrict__ addsrc,
                 long aB, long bB, long biasB, long tabB, long cB)
{
    // ---- XCD-aware remap: XCD c gets contiguous logical chunk ----
    const int nx = gridDim.x, ny = gridDim.y;
    long nwg = (long)nx * ny * gridDim.z;
    long flat = blockIdx.x + (long)nx * (blockIdx.y + (long)ny * blockIdx.z);
    long cpx = nwg >> 3;                       // nwg % 8 == 0 by construction
    long swz = (flat & 7) * cpx + (flat >> 3);
    const int bx = (int)(swz % nx);
    const int by = (int)((swz / nx) % ny);
    const int bz = (int)(swz / ((long)nx * ny));

    A  += (long)bz * aB;
    Bt += (long)bz * bB;
    const float* bptr = bias + (long)bz * biasB;
    const int* tab = idxTab ? idxTab + (long)bz * tabB : nullptr;
    float*          Cf = (float*)Cv + (long)bz * cB;
    unsigned short* Cb = (unsigned short*)Cv + (long)bz * cB;

    const int m0 = by * 256, n0 = bx * 128;

    // empty-tile early-exit (uniform across block; before any barrier)
    if ((GATHER || SCATTER) && tab[m0] < 0) return;

    __shared__ unsigned short As[256][64];   // 32 KB, row = m
    __shared__ unsigned short Bs[128][64];   // 16 KB, row = n  (48 KB total)

    const int tid  = threadIdx.x;
    const int wv   = tid >> 6;               // 0..7
    const int lane = tid & 63;

    // staging: issue = 8 rows x 128 B = 1024 B = 64 lanes x 16 B.
    const int srow = lane >> 3;
    const int schk = lane & 7;

    const unsigned short* aSrc[4];           // wave stages A rows wv*32..+31
    const unsigned short* bSrc[2];           // wave stages B rows wv*16..+15
    #pragma unroll
    for (int i = 0; i < 4; ++i) {
        int lrow = wv * 32 + i * 8 + srow;          // 0..255
        int scol = ((schk ^ (lrow & 7)) * 8);       // swizzled col (elems)
        long sr;
        if (GATHER) { int tr = tab[m0 + lrow]; sr = tr < 0 ? 0 : tr; }
        else        sr = m0 + lrow;
        aSrc[i] = A + sr * (long)K + scol;
    }
    #pragma unroll
    for (int i = 0; i < 2; ++i) {
        int lrow = wv * 16 + i * 8 + srow;          // 0..127
        int scol = ((schk ^ (lrow & 7)) * 8);
        bSrc[i] = Bt + (long)(n0 + lrow) * K + scol;
    }

    f32x4 acc[4][4] = {};
    const int wm = wv >> 1, wn = wv & 1;     // 4 x 2 wave grid
    const int fr = lane & 15, kg = lane >> 4;

    for (int k0 = 0; k0 < K; k0 += 64) {
        __syncthreads();                     // prev tile fully consumed
        #pragma unroll
        for (int i = 0; i < 4; ++i)
            gload_lds16(aSrc[i] + k0, &As[wv * 32 + i * 8][0]);
        #pragma unroll
        for (int i = 0; i < 2; ++i)
            gload_lds16(bSrc[i] + k0, &Bs[wv * 16 + i * 8][0]);
        __syncthreads();                     // vmcnt(0) drained here

        #pragma unroll
        for (int kk = 0; kk < 2; ++kk) {     // two K=32 halves of BK=64
            bf16x8 af[4], bfr[4];
            #pragma unroll
            for (int i2 = 0; i2 < 4; ++i2) {
                int R = wm * 64 + i2 * 16 + fr;
                af[i2] = *(const bf16x8*)&As[R][((kk * 4 + kg) ^ (R & 7)) * 8];
            }
            #pragma unroll
            for (int j2 = 0; j2 < 4; ++j2) {
                int R = wn * 64 + j2 * 16 + fr;
                bfr[j2] = *(const bf16x8*)&Bs[R][((kk * 4 + kg) ^ (R & 7)) * 8];
            }
            #pragma unroll
            for (int i2 = 0; i2 < 4; ++i2)
                #pragma unroll
                for (int j2 = 0; j2 < 4; ++j2)
                    acc[i2][j2] = __builtin_amdgcn_mfma_f32_16x16x32_bf16(
                        af[i2], bfr[j2], acc[i2][j2], 0, 0, 0);
        }
    }

    // epilogue: C/D layout col = lane&15, row = (lane>>4)*4 + r
    const int colL = lane & 15, rgrp = (lane >> 4) * 4;
    #pragma unroll
    for (int i2 = 0; i2 < 4; ++i2) {
        #pragma unroll
        for (int r = 0; r < 4; ++r) {
            int gm = m0 + wm * 64 + i2 * 16 + rgrp + r;
            int token = gm; float sc = 1.0f;
            if (SCATTER) {
                token = tab[gm];
                if (token < 0) continue;
                sc = rs[token];
            } else if (ROWSCALE) {
                sc = rs[gm];
            }
            #pragma unroll
            for (int j2 = 0; j2 < 4; ++j2) {
                int gn = n0 + wn * 64 + j2 * 16 + colL;
                float v = acc[i2][j2][r] + bptr[gn];
                if (RELU) v = fmaxf(v, 0.0f);
                if (SCATTER) {
                    long idx = (long)token * N + gn;
                    if (OUTBF16) Cb[idx] = f2bf(addsrc[idx] + v * sc);  // fused cast
                    else         Cf[idx] += v * sc;                     // f32 RMW
                } else {
                    if (ROWSCALE) v *= sc;
                    if (OUTBF16) Cb[(long)gm * N + gn] = f2bf(v);
                    else         Cf[(long)gm * N + gn] = v;
                }
            }
        }
    }
}

// ---------------------------------------------------------------------------
// Dropped-token rows: mixb[row] = bf16(mix[row]) for rows never touched by
// the scatter GEMM.
// ---------------------------------------------------------------------------
__global__ __launch_bounds__(256)
void drop_cast_k(const float* __restrict__ mix, unsigned short* __restrict__ mixb,
                 const int* __restrict__ droplist, const int* __restrict__ dropcnt)
{
    const int cnt = *dropcnt;
    for (int i = blockIdx.x; i < cnt; i += gridDim.x) {
        const int tok = droplist[i];
        const float4* src = (const float4*)(mix + (long)tok * HD);
        ushort4* dst = (ushort4*)(mixb + (long)tok * HD);
        const int j = threadIdx.x;          // 256 threads x 4 elems = 1024
        float4 v = src[j];
        ushort4 o;
        o.x = f2bf(v.x); o.y = f2bf(v.y); o.z = f2bf(v.z); o.w = f2bf(v.w);
        dst[j] = o;
    }
}

// ---------------------------------------------------------------------------
// Transpose + cast: W[K][N] f32 -> Wt[N][K] bf16, 64x64 LDS tiles. z batched.
// ---------------------------------------------------------------------------
__global__ __launch_bounds__(256)
void transpose_cast_k(const float* __restrict__ W, unsigned short* __restrict__ Wt,
                      int K, int N, long wB, long wtB)
{
    const int z = blockIdx.z;
    W  += (long)z * wB;
    Wt += (long)z * wtB;
    __shared__ float tile[64][65];
    const int k0 = blockIdx.x * 64, n0 = blockIdx.y * 64;
    const int c = threadIdx.x & 63, r4 = threadIdx.x >> 6;
    #pragma unroll 4
    for (int it = 0; it < 16; ++it) {
        int row = it * 4 + r4;
        tile[row][c] = W[(long)(k0 + row) * N + n0 + c];
    }
    __syncthreads();
    #pragma unroll 4
    for (int it = 0; it < 16; ++it) {
        int nrow = it * 4 + r4;
        Wt[(long)(n0 + nrow) * K + k0 + c] = f2bf(tile[c][nrow]);
    }
}

// ---------------------------------------------------------------------------
// Wsmall: Wg'[H][8] = W_in @ W_gate, Wc'[H][2] = W_in @ W_coef  (f32)
// ---------------------------------------------------------------------------
__global__ __launch_bounds__(256)
void wsmall_k(const float* __restrict__ W_in, const float* __restrict__ W_gate,
              const float* __restrict__ W_coef,
              float* __restrict__ wgp, float* __restrict__ wcp)
{
    const int r = blockIdx.x * 4 + (threadIdx.x >> 6);
    const int lane = threadIdx.x & 63;
    float s[10] = {};
    for (int k = lane; k < HD; k += 64) {
        float a = W_in[(long)r * HD + k];
        const float4* g = (const float4*)(W_gate + (long)k * 8);
        float4 g0 = g[0], g1 = g[1];
        s[0] += a * g0.x; s[1] += a * g0.y; s[2] += a * g0.z; s[3] += a * g0.w;
        s[4] += a * g1.x; s[5] += a * g1.y; s[6] += a * g1.z; s[7] += a * g1.w;
        float2 cv = *(const float2*)(W_coef + (long)k * 2);
        s[8] += a * cv.x; s[9] += a * cv.y;
    }
    #pragma unroll
    for (int off = 32; off > 0; off >>= 1)
        #pragma unroll
        for (int e = 0; e < 10; ++e) s[e] += __shfl_xor(s[e], off);
    if (lane == 0) {
        #pragma unroll
        for (int e = 0; e < 8; ++e) wgp[(long)r * 8 + e] = s[e];
        wcp[(long)r * 2 + 0] = s[8];
        wcp[(long)r * 2 + 1] = s[9];
    }
}

// bg[8] = b_in @ W_gate ; bc[2] = b_in @ W_coef + b_coef
__global__ void gbias_k(const float* __restrict__ b_in, const float* __restrict__ W_gate,
                        const float* __restrict__ W_coef, const float* __restrict__ b_coef,
                        float* __restrict__ bg, float* __restrict__ bc)
{
    const int lane = threadIdx.x;  // 64
    float s[10] = {};
    for (int k = lane; k < HD; k += 64) {
        float a = b_in[k];
        const float4* g = (const float4*)(W_gate + (long)k * 8);
        float4 g0 = g[0], g1 = g[1];
        s[0] += a * g0.x; s[1] += a * g0.y; s[2] += a * g0.z; s[3] += a * g0.w;
        s[4] += a * g1.x; s[5] += a * g1.y; s[6] += a * g1.z; s[7] += a * g1.w;
        float2 cv = *(const float2*)(W_coef + (long)k * 2);
        s[8] += a * cv.x; s[9] += a * cv.y;
    }
    #pragma unroll
    for (int off = 32; off > 0; off >>= 1)
        #pragma unroll
        for (int e = 0; e < 10; ++e) s[e] += __shfl_xor(s[e], off);
    if (lane == 0) {
        #pragma unroll
        for (int e = 0; e < 8; ++e) bg[e] = s[e];
        bc[0] = s[8] + b_coef[0];
        bc[1] = s[9] + b_coef[1];
    }
}

// ---------------------------------------------------------------------------
// Gating from x with fused weights (one wave per token) + fused x->bf16 cast.
// ---------------------------------------------------------------------------
__global__ __launch_bounds__(256)
void gating_k(const float* __restrict__ x,
              const float* __restrict__ Wg,   // [H,8] fused
              const float* __restrict__ Wc,   // [H,2] fused
              const float* __restrict__ bg,   // [8]
              const float* __restrict__ bc,   // [2]
              unsigned short* __restrict__ xb,
              int* __restrict__ eidx,
              float* __restrict__ gval,
              float* __restrict__ coef0,
              float* __restrict__ coef1)
{
    const int tok = (blockIdx.x * 256 + threadIdx.x) >> 6;
    const int lane = threadIdx.x & 63;
    const float* row = x + (long)tok * HD;
    unsigned short* orow = xb + (long)tok * HD;

    float acc[8] = {};
    float c0 = 0.f, c1 = 0.f;
    for (int i = 0; i < HD / 64; ++i) {
        int k = i * 64 + lane;
        float tv = row[k];
        orow[k] = f2bf(tv);                      // fused x -> bf16 (coalesced)
        const float4* wg = (const float4*)(Wg + (long)k * 8);
        float4 w0 = wg[0], w1 = wg[1];
        acc[0] = fmaf(tv, w0.x, acc[0]); acc[1] = fmaf(tv, w0.y, acc[1]);
        acc[2] = fmaf(tv, w0.z, acc[2]); acc[3] = fmaf(tv, w0.w, acc[3]);
        acc[4] = fmaf(tv, w1.x, acc[4]); acc[5] = fmaf(tv, w1.y, acc[5]);
        acc[6] = fmaf(tv, w1.z, acc[6]); acc[7] = fmaf(tv, w1.w, acc[7]);
        float2 wcv = *(const float2*)(Wc + (long)k * 2);
        c0 = fmaf(tv, wcv.x, c0);
        c1 = fmaf(tv, wcv.y, c1);
    }
    #pragma unroll
    for (int off = 32; off > 0; off >>= 1) {
        #pragma unroll
        for (int e = 0; e < 8; ++e) acc[e] += __shfl_xor(acc[e], off);
        c0 += __shfl_xor(c0, off);
        c1 += __shfl_xor(c1, off);
    }
    if (lane == 0) {
        #pragma unroll
        for (int e = 0; e < 8; ++e) acc[e] += bg[e];
        float m = acc[0]; int best = 0;
        #pragma unroll
        for (int e = 1; e < 8; ++e) if (acc[e] > m) { m = acc[e]; best = e; }
        float s = 0.f;
        #pragma unroll
        for (int e = 0; e < 8; ++e) s += expf(acc[e] - m);
        eidx[tok] = best;
        gval[tok] = 1.0f / s;
        float l0 = c0 + bc[0], l1 = c1 + bc[1];
        float mm = fmaxf(l0, l1);
        float e0 = expf(l0 - mm), e1 = expf(l1 - mm);
        float inv = 1.0f / (e0 + e1);
        coef0[tok] = e0 * inv;
        coef1[tok] = e1 * inv;
    }
}

// ---------------------------------------------------------------------------
// Parallel capacity scan, 3 phases (integer-exact, verified round 5).
// ---------------------------------------------------------------------------
__global__ void scan_hist_k(const int* __restrict__ eidx,
                            int* __restrict__ counts,
                            int* __restrict__ idxTab)
{
    const int b = blockIdx.x;          // chunk id, 0..255
    const int lane = threadIdx.x;      // 64
    for (int j = b * 64 + lane; j < NE * CAP; j += NCHUNK * 64)
        idxTab[j] = -1;
    int e = eidx[b * 64 + lane];
    #pragma unroll
    for (int ex = 0; ex < NE; ++ex) {
        unsigned long long msk = __ballot(e == ex);
        if (lane == ex) counts[b * NE + ex] = (int)__popcll(msk);
    }
}

__global__ void scan_offsets_k(const int* __restrict__ counts,
                               int* __restrict__ offsets,
                               int* __restrict__ dropcnt)
{
    const int e = threadIdx.x;         // 64 threads, 8 active
    if (e == 63) *dropcnt = 0;         // runs before scan_fill_k
    if (e < NE) {
        int run = 0;
        for (int b = 0; b < NCHUNK; ++b) {
            offsets[b * NE + e] = run;
            run += counts[b * NE + e];
        }
    }
}

__global__ void scan_fill_k(const int* __restrict__ eidx,
                            const float* __restrict__ gval,
                            const float* __restrict__ coef0,
                            const int* __restrict__ offsets,
                            int* __restrict__ idxTab,
                            float* __restrict__ smoe,
                            int* __restrict__ droplist,
                            int* __restrict__ dropcnt)
{
    const int b = blockIdx.x;
    const int lane = threadIdx.x;
    const int tok = b * 64 + lane;
    int e = eidx[tok];
    unsigned long long below = (lane == 0) ? 0ull : ((~0ull) >> (64 - lane));
    int myrank = 0;
    #pragma unroll
    for (int ex = 0; ex < NE; ++ex) {
        unsigned long long msk = __ballot(e == ex);
        if (e == ex) myrank = (int)__popcll(msk & below) + offsets[b * NE + ex];
    }
    if (myrank < CAP) {
        idxTab[e * CAP + myrank] = tok;
        smoe[tok] = gval[tok] * coef0[tok];
    } else {
        smoe[tok] = 0.0f;
        int di = atomicAdd(dropcnt, 1);    // order varies; content is a set
        droplist[di] = tok;
    }
}

// ---------------------------------------------------------------------------
// Workspace plan (lifetime-aliased; ~135 MB):
//   slotA [0,32Mi):   W1T then res1 then mixb
//   h     [32,72Mi);  t_b [72,104Mi); W2T [104,120Mi);
//   WinT/Wr1T/Wr2T/WoutT [120..128Mi); small [128Mi..)
//   xb: d_out[0,32Mi);  mix: d_out f32 (read-only after j);  out: d_out
// ---------------------------------------------------------------------------
extern "C" void kernel_launch(void* const* d_in, const int* in_sizes, int n_in,
                              void* d_out, int out_size, void* d_ws, size_t ws_size,
                              hipStream_t stream)
{
    const float* x      = (const float*)d_in[0];
    const float* W_in   = (const float*)d_in[1];
    const float* b_in   = (const float*)d_in[2];
    const float* W_gate = (const float*)d_in[3];
    const float* W1     = (const float*)d_in[4];
    const float* b1     = (const float*)d_in[5];
    const float* W2     = (const float*)d_in[6];
    const float* b2     = (const float*)d_in[7];
    const float* Wr1    = (const float*)d_in[8];
    const float* br1    = (const float*)d_in[9];
    const float* Wr2    = (const float*)d_in[10];
    const float* br2    = (const float*)d_in[11];
    const float* W_coef = (const float*)d_in[12];
    const float* b_coef = (const float*)d_in[13];
    const float* W_out  = (const float*)d_in[14];
    const float* b_out  = (const float*)d_in[15];
    float* out = (float*)d_out;

    const size_t MiB = 1024 * 1024;
    char* ws = (char*)d_ws;
    unsigned short* W1T  = (unsigned short*)(ws + 0);          // 16 MiB
    unsigned short* res1 = (unsigned short*)(ws + 0);          // 32 MiB (after FC1)
    unsigned short* mixb = (unsigned short*)(ws + 0);          // 32 MiB (after res-mix)
    unsigned short* h    = (unsigned short*)(ws + 32 * MiB);   // 40 MiB
    unsigned short* t_b  = (unsigned short*)(ws + 72 * MiB);   // 32 MiB
    unsigned short* W2T  = (unsigned short*)(ws + 104 * MiB);  // 16 MiB
    unsigned short* WinT = (unsigned short*)(ws + 120 * MiB);  // 2 MiB
    unsigned short* Wr1T = (unsigned short*)(ws + 122 * MiB);  // 2 MiB
    unsigned short* Wr2T = (unsigned short*)(ws + 124 * MiB);  // 2 MiB
    unsigned short* WoutT= (unsigned short*)(ws + 126 * MiB);  // 2 MiB
    char* sm = ws + 128 * MiB;
    float* wgp  = (float*)(sm);            sm += HD * 8 * 4;
    float* wcp  = (float*)(sm);            sm += HD * 2 * 4;
    float* bg   = (float*)(sm);            sm += 64;
    float* bc   = (float*)(sm);            sm += 64;
    int*   eidx = (int*)(sm);              sm += T_TOK * 4;
    float* gval = (float*)(sm);            sm += T_TOK * 4;
    float* cf0  = (float*)(sm);            sm += T_TOK * 4;
    float* cf1  = (float*)(sm);            sm += T_TOK * 4;
    float* smoe = (float*)(sm);            sm += T_TOK * 4;
    int* idxTab = (int*)(sm);              sm += NE * CAP * 4;
    int* counts = (int*)(sm);              sm += NCHUNK * NE * 4;
    int* offs   = (int*)(sm);              sm += NCHUNK * NE * 4;
    int* droplist = (int*)(sm);            sm += T_TOK * 4;
    int* dropcnt  = (int*)(sm);            sm += 64;
    unsigned short* xb = (unsigned short*)d_out;   // 32 MiB, dies after f
    float* mix = out;                               // f32, written j, read k/m
    (void)ws_size; (void)in_sizes; (void)n_in; (void)out_size;

    dim3 blk(256);
    dim3 blkG(512);
    dim3 gT(16, 16, 1);
    dim3 gT8(16, 16, 8);
    dim3 gBig(HD / 128, T_TOK / 256, 1);   // 8 x 64 = 512 blocks (%8==0)
    dim3 gExp(HD / 128, CAP / 256, NE);    // 8 x 10 x 8 = 640 blocks (%8==0)

    // b. weight transposes (bf16 [N][K])
    transpose_cast_k<<<gT,  blk, 0, stream>>>(W_in,  WinT,  HD, HD, 0, 0);
    transpose_cast_k<<<gT,  blk, 0, stream>>>(Wr1,   Wr1T,  HD, HD, 0, 0);
    transpose_cast_k<<<gT,  blk, 0, stream>>>(Wr2,   Wr2T,  HD, HD, 0, 0);
    transpose_cast_k<<<gT,  blk, 0, stream>>>(W_out, WoutT, HD, HD, 0, 0);
    transpose_cast_k<<<gT8, blk, 0, stream>>>(W1, W1T, HD, HD, (long)HD * HD, (long)HD * HD);
    transpose_cast_k<<<gT8, blk, 0, stream>>>(W2, W2T, HD, HD, (long)HD * HD, (long)HD * HD);
    // c. fused gating weights (f32)
    wsmall_k<<<HD / 4, blk, 0, stream>>>(W_in, W_gate, W_coef, wgp, wcp);
    gbias_k<<<1, 64, 0, stream>>>(b_in, W_gate, W_coef, b_coef, bg, bc);
    // d. gating from x (f32 routing path) + fused x->bf16 cast
    gating_k<<<T_TOK / 4, blk, 0, stream>>>(x, wgp, wcp, bg, bc, xb,
                                            eidx, gval, cf0, cf1);
    // e. parallel capacity scan (+ dropped-token list)
    scan_hist_k<<<NCHUNK, 64, 0, stream>>>(eidx, counts, idxTab);
    scan_offsets_k<<<1, 64, 0, stream>>>(counts, offs, dropcnt);
    scan_fill_k<<<NCHUNK, 64, 0, stream>>>(eidx, gval, cf0, offs, idxTab, smoe,
                                           droplist, dropcnt);
    // f. t_b = bf16(xb @ W_in + b_in)
    gemm_bf16_k<false, false, false, false, true><<<gBig, blkG, 0, stream>>>(
        xb, WinT, b_in, t_b, T_TOK, HD, HD, nullptr, nullptr, nullptr,
        0, 0, 0, 0, 0);
    // h. h[e] = relu(gather(t_b) @ W1[e] + b1[e])   bf16 out, empty-tile exit
    gemm_bf16_k<true, true, false, false, true><<<gExp, blkG, 0, stream>>>(
        t_b, W1T, b1, h, CAP, HD, HD, idxTab, nullptr, nullptr,
        0, (long)HD * HD, HD, CAP, (long)CAP * HD);
    // i. res1 = relu(t_b @ Wr1 + br1)   bf16 out (overlays W1T slot)
    gemm_bf16_k<false, true, false, false, true><<<gBig, blkG, 0, stream>>>(
        t_b, Wr1T, br1, res1, T_TOK, HD, HD, nullptr, nullptr, nullptr,
        0, 0, 0, 0, 0);
    // j. mix = (res1 @ Wr2 + br2) * cf1[row]   f32 -> d_out
    gemm_bf16_k<false, false, true, false, false><<<gBig, blkG, 0, stream>>>(
        res1, Wr2T, br2, mix, T_TOK, HD, HD, nullptr, cf1, nullptr,
        0, 0, 0, 0, 0);
    // k. mixb[tok] = bf16(mix[tok] + (h[e]@W2[e]+b2[e])*smoe[tok])  fused cast,
    //    empty-tile exit
    gemm_bf16_k<false, false, false, true, true><<<gExp, blkG, 0, stream>>>(
        h, W2T, b2, mixb, CAP, HD, HD, idxTab, smoe, mix,
        (long)CAP * HD, (long)HD * HD, HD, CAP, 0);
    // k2. dropped-token rows: mixb = bf16(mix)
    drop_cast_k<<<256, blk, 0, stream>>>(mix, mixb, droplist, dropcnt);
    // m. out = mixb @ W_out + b_out   f32 -> d_out
    gemm_bf16_k<false, false, false, false, false><<<gBig, blkG, 0, stream>>>(
        mixb, WoutT, b_out, out, T_TOK, HD, HD, nullptr, nullptr, nullptr,
        0, 0, 0, 0, 0);
}